// Round 20
// baseline (245.311 us; speedup 1.0000x reference)
//
#include <hip/hip_runtime.h>

#define RPB  32     // rows per block
#define NTHR 64     // 1 wave: owns 32 rows x ALL 128 cols -> zero barriers

typedef _Float16 f16;
typedef _Float16 f16x4 __attribute__((ext_vector_type(4)));
typedef _Float16 f16x8 __attribute__((ext_vector_type(8)));
typedef float    f32x4 __attribute__((ext_vector_type(4)));

// ---- workspace layout: weights packed to f16 in fragment order ----
#define G_MW2 1024                 // 128*64/8
#define G_W   2048                 // 128*128/8
#define G_MW3 16384                // 1024*128/8
#define GO_MW2 0
#define GO_W2  (GO_MW2 + G_MW2)
#define GO_W3  (GO_W2 + G_W)
#define GO_W4  (GO_W3 + G_W)
#define GO_MW3 (GO_W4 + G_W)
#define G_TOT  (GO_MW3 + G_MW3)    // 23552 f16x8 groups
#define G_MW1Q 256                 // mw1: 4 frags x 64 lanes of f16x4 (16x16x16)
#define WS_BYTES ((size_t)G_TOT * 16 + (size_t)G_MW1Q * 8)

// ---- LDS layout (bytes), per 32-row block ----
// sH2[32][136]=8704 ; region B: sY[32][136]=8704 ∪ sH1[32][72]=4608 ; sX[32]=128
#define OFF_H2    0
#define OFF_B     8704
#define OFF_H1    (OFF_B)
#define OFF_X     (OFF_B + 8704)       // 17408
#define SMEM_SZ   (OFF_X + 128)        // 17536 -> 8 blocks/CU by LDS

__device__ __forceinline__ f16x8 cvt8(const float* __restrict__ p) {
  const float4* p4 = (const float4*)p;
  float4 f0 = p4[0], f1 = p4[1];
  f16x8 o;
  o[0]=(f16)f0.x; o[1]=(f16)f0.y; o[2]=(f16)f0.z; o[3]=(f16)f0.w;
  o[4]=(f16)f1.x; o[5]=(f16)f1.y; o[6]=(f16)f1.z; o[7]=(f16)f1.w;
  return o;
}

__device__ __forceinline__ f16x4 cvt4v(float4 f) {
  f16x4 o;
  o[0]=(f16)f.x; o[1]=(f16)f.y; o[2]=(f16)f.z; o[3]=(f16)f.w;
  return o;
}

__global__ void pack_weights(const float* __restrict__ mw1, const float* __restrict__ mw2,
                             const float* __restrict__ w2,  const float* __restrict__ w3,
                             const float* __restrict__ w4,  const float* __restrict__ mw3,
                             f16x8* __restrict__ ws) {
  int g = blockIdx.x * blockDim.x + threadIdx.x;
  if (g >= G_TOT + G_MW1Q) return;
  if (g >= G_TOT) {                 // mw1: 16x16x16 A-frags (f16x4)
    const int local = g - G_TOT;
    const int lane = local & 63, jt = local >> 6;
    const int j = jt * 16 + (lane & 15);
    const int k0 = (lane >> 4) * 4;
    ((f16x4*)(ws + G_TOT))[local] = cvt4v(*(const float4*)(mw1 + j * 16 + k0));
    return;
  }
  if (g < GO_MW3) {                 // linear-packed matrices
    const float* W; int K; int local;
    if (g < GO_W2)       { W = mw2; K = 64;  local = g; }
    else if (g < GO_W3)  { W = w2;  K = 128; local = g - GO_W2; }
    else if (g < GO_W4)  { W = w3;  K = 128; local = g - GO_W3; }
    else                 { W = w4;  K = 128; local = g - GO_W4; }
    const int lane = local & 63, fb = local >> 6;
    const int ksteps = K >> 5;
    const int ks = fb % ksteps, n0g = fb / ksteps;
    const int n  = n0g * 16 + (lane & 15);
    const int k0 = ks * 32 + (lane >> 4) * 8;
    ws[g] = cvt8(W + (size_t)n * K + k0);
  } else {                          // mw3: AdaIN-interleaved
    const int local = g - GO_MW3;
    const int lane = local & 63, fb = local >> 6;   // fb: l(2) ch(1) tt(2) sb(1) ks(2)
    const int ks = fb & 3, sb = (fb >> 2) & 1, tt = (fb >> 3) & 3;
    const int ch = (fb >> 5) & 1, l = fb >> 6;
    const int n  = l * 256 + 2 * (ch * 64 + tt * 16 + (lane & 15)) + sb;
    const int k0 = ks * 32 + (lane >> 4) * 8;
    ws[g] = cvt8(mw3 + (size_t)n * 128 + k0);
  }
}

template<bool WS>
__device__ __forceinline__ f16x8 ldB(const f16x8* __restrict__ wp,
                                     const float* __restrict__ wf,
                                     int K, int n0, int ks, int lane) {
  if constexpr (WS) {
    return wp[((n0 >> 4) * (K >> 5) + ks) * 64 + lane];
  } else {
    const int n  = n0 + (lane & 15);
    const int k0 = ks * 32 + (lane >> 4) * 8;
    return cvt8(wf + (size_t)n * K + k0);
  }
}

template<bool WS>
__device__ __forceinline__ f16x8 ldB3(const f16x8* __restrict__ wp,
                                      const float* __restrict__ wf,
                                      int l, int ch, int tt, int sb, int ks, int lane) {
  if constexpr (WS) {
    const int fb = (((l * 2 + ch) * 4 + tt) * 2 + sb) * 4 + ks;
    return wp[fb * 64 + lane];
  } else {
    const int n  = l * 256 + 2 * (ch * 64 + tt * 16 + (lane & 15)) + sb;
    const int k0 = ks * 32 + (lane >> 4) * 8;
    return cvt8(wf + (size_t)n * 128 + k0);
  }
}

template<bool WS>
__device__ __forceinline__ f16x4 ldB1(const f16x8* __restrict__ wsp,
                                      const float* __restrict__ mw1f,
                                      int jt, int lane) {
  if constexpr (WS) {
    return ((const f16x4*)(wsp + G_TOT))[jt * 64 + lane];
  } else {
    const int j = jt * 16 + (lane & 15);
    const int k0 = (lane >> 4) * 4;
    return cvt4v(*(const float4*)(mw1f + j * 16 + k0));
  }
}

#define MFMA(a, b, c)   __builtin_amdgcn_mfma_f32_16x16x32_f16((a), (b), (c), 0, 0, 0)
#define MFMA16(a, b, c) __builtin_amdgcn_mfma_f32_16x16x16f16((a), (b), (c), 0, 0, 0)

template<bool WS>
__global__ __launch_bounds__(NTHR, 2)   // 2 waves/EU band; arch-VGPR budget ~128
void adain_mfma(const float* __restrict__ x,   const float* __restrict__ meta,
                const float* __restrict__ mw1, const float* __restrict__ mb1,
                const float* __restrict__ mw2, const float* __restrict__ mb2,
                const float* __restrict__ mw3, const float* __restrict__ mb3,
                const float* __restrict__ w1,  const float* __restrict__ b1,
                const float* __restrict__ w2,  const float* __restrict__ b2,
                const float* __restrict__ w3,  const float* __restrict__ b3,
                const float* __restrict__ w4,  const float* __restrict__ b4,
                const float* __restrict__ w5,  const float* __restrict__ b5,
                const f16x8* __restrict__ wsp, float* __restrict__ out)
{
  __shared__ __align__(16) char smem[SMEM_SZ];
  f16    (*sH2)[136]   = (f16(*)[136])  (smem + OFF_H2);
  f16    (*sH1)[72]    = (f16(*)[72])   (smem + OFF_H1);
  f16    (*sY)[136]    = (f16(*)[136])  (smem + OFF_B);
  float  *sX           = (float*)       (smem + OFF_X);

  const int lane = threadIdx.x;       // single wave
  const int r0   = blockIdx.x * RPB;
  const int ln   = lane & 15;         // row index within 16-row stripe (D^T layout)
  const int bg   = lane >> 4;         // k-subgroup / channel quad
  const int acol = bg * 8;
  const int g4   = bg * 4;            // channel base offset within 16-chan tile

  const f16x8* wsp3 = wsp + GO_MW3;

  // ---- stage x (same-wave consumers; lgkmcnt handles ordering) ----
  if (lane < RPB) sX[lane] = x[r0 + lane];

  // ---- h1 = relu(meta @ mw1.T + mb1) via MFMA 16x16x16, meta from global ----
  {
    f16x4 am[2];
#pragma unroll
    for (int p = 0; p < 2; ++p)
      am[p] = cvt4v(*(const float4*)(meta + (size_t)(r0 + p * 16 + ln) * 16 + g4));
#pragma unroll
    for (int jt = 0; jt < 4; ++jt) {
      const f16x4 wj = ldB1<WS>(wsp, mw1, jt, lane);
      const float4 bb = *(const float4*)(mb1 + jt * 16 + g4);
      const f32x4 cini = {bb.x, bb.y, bb.z, bb.w};
#pragma unroll
      for (int p = 0; p < 2; ++p) {
        f32x4 acc = MFMA16(wj, am[p], cini);
        f16x4 hv;
#pragma unroll
        for (int q = 0; q < 4; ++q) hv[q] = (f16)fmaxf(acc[q], 0.0f);
        *(f16x4*)&sH1[p * 16 + ln][jt * 16 + g4] = hv;
      }
    }
  }

  // ---- h2 = relu(h1 @ mw2.T + mb2), transposed-D, bias in C ----
  {
    f16x8 a0[2], a1[2];
#pragma unroll
    for (int p = 0; p < 2; ++p) {
      const int ar = p * 16 + ln;
      a0[p] = *(const f16x8*)&sH1[ar][acol];
      a1[p] = *(const f16x8*)&sH1[ar][32 + acol];
    }
#pragma unroll
    for (int tt = 0; tt < 8; ++tt) {
      const int n0 = tt * 16;
      f16x8 b0 = ldB<WS>(wsp + GO_MW2, mw2, 64, n0, 0, lane);
      f16x8 b1 = ldB<WS>(wsp + GO_MW2, mw2, 64, n0, 1, lane);
      const float4 bb = *(const float4*)(mb2 + n0 + g4);
      const f32x4 cini = {bb.x, bb.y, bb.z, bb.w};
#pragma unroll
      for (int p = 0; p < 2; ++p) {
        f32x4 acc = MFMA(b0, a0[p], cini);
        acc = MFMA(b1, a1[p], acc);
        f16x4 hv;
#pragma unroll
        for (int q = 0; q < 4; ++q) hv[q] = (f16)fmaxf(acc[q], 0.0f);
        *(f16x4*)&sH2[p * 16 + ln][n0 + g4] = hv;
      }
    }
  }

  // ---- 4 AdaIN layers, fully wave-local: NO barriers ----
#pragma unroll 1
  for (int l = 0; l < 4; ++l) {
    // ---- phase B: main pre-activation (transposed-D, bias in C) ----
    f32x4 accM[2][8];

    if (l == 0) {
#pragma unroll
      for (int tt = 0; tt < 8; ++tt) {
        const int c4 = tt * 16 + g4;
        const float4 w1v = *(const float4*)(w1 + c4);
        const float4 b1v = *(const float4*)(b1 + c4);
#pragma unroll
        for (int p = 0; p < 2; ++p) {
          const float xv = sX[p * 16 + ln];
          accM[p][tt][0] = xv * w1v.x + b1v.x;
          accM[p][tt][1] = xv * w1v.y + b1v.y;
          accM[p][tt][2] = xv * w1v.z + b1v.z;
          accM[p][tt][3] = xv * w1v.w + b1v.w;
        }
      }
    } else {
      const f16x8* Wp_ = (l == 1) ? wsp + GO_W2 : (l == 2) ? wsp + GO_W3 : wsp + GO_W4;
      const float* Wf_ = (l == 1) ? w2 : (l == 2) ? w3 : w4;
      const float* Bv_ = (l == 1) ? b2 : (l == 2) ? b3 : b4;
#pragma unroll
      for (int tt = 0; tt < 8; ++tt) {
        const float4 bv = *(const float4*)(Bv_ + tt * 16 + g4);
        const f32x4 cini = {bv.x, bv.y, bv.z, bv.w};
#pragma unroll
        for (int p = 0; p < 2; ++p)
          accM[p][tt] = cini;
      }
#pragma unroll
      for (int ks = 0; ks < 4; ++ks) {
        f16x8 aY[2];
#pragma unroll
        for (int p = 0; p < 2; ++p)
          aY[p] = *(const f16x8*)&sY[p * 16 + ln][ks * 32 + acol];
#pragma unroll
        for (int tt = 0; tt < 8; ++tt) {
          const f16x8 bm = ldB<WS>(Wp_, Wf_, 128, tt * 16, ks, lane);
#pragma unroll
          for (int p = 0; p < 2; ++p)
            accM[p][tt] = MFMA(bm, aY[p], accM[p][tt]);
        }
      }
    }

    // ---- stats: row r's 32 values live in 4 lanes -> 2 shuffles, no LDS ----
    float s1[2] = {0, 0}, s2[2] = {0, 0};
#pragma unroll
    for (int p = 0; p < 2; ++p)
#pragma unroll
      for (int tt = 0; tt < 8; ++tt)
#pragma unroll
        for (int q = 0; q < 4; ++q) {
          const float v = accM[p][tt][q];
          s1[p] += v; s2[p] += v * v;
        }
#pragma unroll
    for (int p = 0; p < 2; ++p) {
      s1[p] += __shfl_xor(s1[p], 16, 64);
      s2[p] += __shfl_xor(s2[p], 16, 64);
      s1[p] += __shfl_xor(s1[p], 32, 64);
      s2[p] += __shfl_xor(s2[p], 32, 64);
    }

    // ---- mu/rsg; z = (v-mu)*rsg f16 -> staged in sY slots (same-lane r/w) ----
#pragma unroll
    for (int p = 0; p < 2; ++p) {
      const int r = p * 16 + ln;
      const float m = s1[p] * (1.0f / 128.0f);
      float var = (s2[p] - s1[p] * m) * (1.0f / 127.0f);
      var = fmaxf(var, 0.0f);
      const float rsg = 1.0f / (sqrtf(var) + 1e-6f);
#pragma unroll
      for (int tt = 0; tt < 8; ++tt) {
        f16x4 zv;
#pragma unroll
        for (int q = 0; q < 4; ++q)
          zv[q] = (f16)((accM[p][tt][q] - m) * rsg);
        *(f16x4*)&sY[r][tt * 16 + g4] = zv;
      }
    }

    // ---- phase A: style MFMA (transposed, mb3 in C) + apply, per tt ----
    f16x8 aH[2][4];
#pragma unroll
    for (int p = 0; p < 2; ++p) {
      const int ar = p * 16 + ln;
#pragma unroll
      for (int ks = 0; ks < 4; ++ks)
        aH[p][ks] = *(const f16x8*)&sH2[ar][ks * 32 + acol];
    }

    if (l < 3) {
#pragma unroll
      for (int tt = 0; tt < 8; ++tt) {
        const int ch_ = tt >> 2, t3 = tt & 3;
        const int c4 = tt * 16 + g4;
        const float4 mv0 = *(const float4*)(mb3 + l * 256 + 2 * c4);      // s0 b0 s1 b1
        const float4 mv1 = *(const float4*)(mb3 + l * 256 + 2 * c4 + 4);  // s2 b2 s3 b3
        const f32x4 scI = {mv0.x, mv0.z, mv1.x, mv1.z};
        const f32x4 biI = {mv0.y, mv0.w, mv1.y, mv1.w};
        f32x4 sc[2], bi[2];
#pragma unroll
        for (int p = 0; p < 2; ++p) { sc[p] = scI; bi[p] = biI; }
#pragma unroll
        for (int ks = 0; ks < 4; ++ks) {
          const f16x8 bs0 = ldB3<WS>(wsp3, mw3, l, ch_, t3, 0, ks, lane);
          const f16x8 bs1 = ldB3<WS>(wsp3, mw3, l, ch_, t3, 1, ks, lane);
#pragma unroll
          for (int p = 0; p < 2; ++p) {
            sc[p] = MFMA(bs0, aH[p][ks], sc[p]);
            bi[p] = MFMA(bs1, aH[p][ks], bi[p]);
          }
        }
#pragma unroll
        for (int p = 0; p < 2; ++p) {
          const int r = p * 16 + ln;
          const f16x4 zv = *(const f16x4*)&sY[r][c4];    // same-lane slot
          f16x4 yv;
#pragma unroll
          for (int q = 0; q < 4; ++q) {
            float v = sc[p][q] * (float)zv[q] + bi[p][q];
            v = fmaxf(v, 0.01f * v);
            yv[q] = (f16)v;
          }
          *(f16x4*)&sY[r][c4] = yv;                      // overwrite z with y
        }
      }
    } else {
      float o[2] = {0, 0};
#pragma unroll
      for (int tt = 0; tt < 8; ++tt) {
        const int ch_ = tt >> 2, t3 = tt & 3;
        const int c4 = tt * 16 + g4;
        const float4 mv0 = *(const float4*)(mb3 + l * 256 + 2 * c4);
        const float4 mv1 = *(const float4*)(mb3 + l * 256 + 2 * c4 + 4);
        const f32x4 scI = {mv0.x, mv0.z, mv1.x, mv1.z};
        const f32x4 biI = {mv0.y, mv0.w, mv1.y, mv1.w};
        const float4 w5v = *(const float4*)(w5 + c4);
        const float w5q[4] = {w5v.x, w5v.y, w5v.z, w5v.w};
        f32x4 sc[2], bi[2];
#pragma unroll
        for (int p = 0; p < 2; ++p) { sc[p] = scI; bi[p] = biI; }
#pragma unroll
        for (int ks = 0; ks < 4; ++ks) {
          const f16x8 bs0 = ldB3<WS>(wsp3, mw3, l, ch_, t3, 0, ks, lane);
          const f16x8 bs1 = ldB3<WS>(wsp3, mw3, l, ch_, t3, 1, ks, lane);
#pragma unroll
          for (int p = 0; p < 2; ++p) {
            sc[p] = MFMA(bs0, aH[p][ks], sc[p]);
            bi[p] = MFMA(bs1, aH[p][ks], bi[p]);
          }
        }
#pragma unroll
        for (int p = 0; p < 2; ++p) {
          const f16x4 zv = *(const f16x4*)&sY[p * 16 + ln][c4];
#pragma unroll
          for (int q = 0; q < 4; ++q) {
            float v = sc[p][q] * (float)zv[q] + bi[p][q];
            v = fmaxf(v, 0.01f * v);
            o[p] += v * w5q[q];
          }
        }
      }
#pragma unroll
      for (int p = 0; p < 2; ++p) {
        o[p] += __shfl_xor(o[p], 16, 64);
        o[p] += __shfl_xor(o[p], 32, 64);
      }
      if (lane < 16) {
#pragma unroll
        for (int p = 0; p < 2; ++p) {
          float v = o[p] + b5[0];
          v = fmaxf(v, 0.01f * v);
          out[r0 + p * 16 + ln] = v;
        }
      }
    }
  }
}

extern "C" void kernel_launch(void* const* d_in, const int* in_sizes, int n_in,
                              void* d_out, int out_size, void* d_ws, size_t ws_size,
                              hipStream_t stream) {
  const float* x    = (const float*)d_in[0];
  const float* meta = (const float*)d_in[1];
  const float* mw1  = (const float*)d_in[2];
  const float* mb1  = (const float*)d_in[3];
  const float* mw2  = (const float*)d_in[4];
  const float* mb2  = (const float*)d_in[5];
  const float* mw3  = (const float*)d_in[6];
  const float* mb3  = (const float*)d_in[7];
  const float* w1   = (const float*)d_in[8];
  const float* b1   = (const float*)d_in[9];
  const float* w2   = (const float*)d_in[10];
  const float* b2   = (const float*)d_in[11];
  const float* w3   = (const float*)d_in[12];
  const float* b3   = (const float*)d_in[13];
  const float* w4   = (const float*)d_in[14];
  const float* b4   = (const float*)d_in[15];
  const float* w5   = (const float*)d_in[16];
  const float* b5   = (const float*)d_in[17];
  float* out = (float*)d_out;

  const int nrows = in_sizes[0];        // 262144
  const int grid  = nrows / RPB;        // 8192

  const bool usews = (ws_size >= WS_BYTES) && (d_ws != nullptr);
  if (usews) {
    f16x8* wsp = (f16x8*)d_ws;
    hipLaunchKernelGGL(pack_weights, dim3((G_TOT + G_MW1Q + 255) / 256), dim3(256), 0, stream,
                       mw1, mw2, w2, w3, w4, mw3, wsp);
    hipLaunchKernelGGL(adain_mfma<true>, dim3(grid), dim3(NTHR), 0, stream,
                       x, meta, mw1, mb1, mw2, mb2, mw3, mb3,
                       w1, b1, w2, b2, w3, b3, w4, b4, w5, b5, wsp, out);
  } else {
    hipLaunchKernelGGL(adain_mfma<false>, dim3(grid), dim3(NTHR), 0, stream,
                       x, meta, mw1, mb1, mw2, mb2, mw3, mb3,
                       w1, b1, w2, b2, w3, b3, w4, b4, w5, b5, (const f16x8*)nullptr, out);
  }
}

// Round 21
// 151.568 us; speedup vs baseline: 1.6185x; 1.6185x over previous
//
#include <hip/hip_runtime.h>

#define RPB  64     // rows per block
#define NTHR 128    // 2 waves: ch = wid (0..1); each wave 64 rows x 64 cols

typedef _Float16 f16;
typedef _Float16 f16x4 __attribute__((ext_vector_type(4)));
typedef _Float16 f16x8 __attribute__((ext_vector_type(8)));
typedef float    f32x4 __attribute__((ext_vector_type(4)));

// ---- workspace layout: weights packed to f16 in fragment order ----
#define G_MW2 1024                 // 128*64/8
#define G_W   2048                 // 128*128/8
#define G_MW3 16384                // 1024*128/8
#define GO_MW2 0
#define GO_W2  (GO_MW2 + G_MW2)
#define GO_W3  (GO_W2 + G_W)
#define GO_W4  (GO_W3 + G_W)
#define GO_MW3 (GO_W4 + G_W)
#define G_TOT  (GO_MW3 + G_MW3)    // 23552 f16x8 groups
#define G_MW1Q 256                 // mw1: 4 frags x 64 lanes of f16x4 (16x16x16)
#define WS_BYTES ((size_t)G_TOT * 16 + (size_t)G_MW1Q * 8)

// ---- LDS layout (bytes), per 64-row block ----
#define OFF_H2    0
#define OFF_B     17408
#define OFF_H1    (OFF_B)
#define OFF_STATS (OFF_B + 17408)      // 34816
#define OFF_OUT   (OFF_STATS + 1024)   // 35840
#define OFF_X     (OFF_OUT + 512)      // 36352
#define SMEM_SZ   (OFF_X + 256)        // 36608

__device__ __forceinline__ f16x8 cvt8(const float* __restrict__ p) {
  const float4* p4 = (const float4*)p;
  float4 f0 = p4[0], f1 = p4[1];
  f16x8 o;
  o[0]=(f16)f0.x; o[1]=(f16)f0.y; o[2]=(f16)f0.z; o[3]=(f16)f0.w;
  o[4]=(f16)f1.x; o[5]=(f16)f1.y; o[6]=(f16)f1.z; o[7]=(f16)f1.w;
  return o;
}

__device__ __forceinline__ f16x4 cvt4v(float4 f) {
  f16x4 o;
  o[0]=(f16)f.x; o[1]=(f16)f.y; o[2]=(f16)f.z; o[3]=(f16)f.w;
  return o;
}

__global__ void pack_weights(const float* __restrict__ mw1, const float* __restrict__ mw2,
                             const float* __restrict__ w2,  const float* __restrict__ w3,
                             const float* __restrict__ w4,  const float* __restrict__ mw3,
                             f16x8* __restrict__ ws) {
  int g = blockIdx.x * blockDim.x + threadIdx.x;
  if (g >= G_TOT + G_MW1Q) return;
  if (g >= G_TOT) {                 // mw1: 16x16x16 A-frags (f16x4)
    const int local = g - G_TOT;
    const int lane = local & 63, jt = local >> 6;
    const int j = jt * 16 + (lane & 15);
    const int k0 = (lane >> 4) * 4;
    ((f16x4*)(ws + G_TOT))[local] = cvt4v(*(const float4*)(mw1 + j * 16 + k0));
    return;
  }
  if (g < GO_MW3) {                 // linear-packed matrices
    const float* W; int K; int local;
    if (g < GO_W2)       { W = mw2; K = 64;  local = g; }
    else if (g < GO_W3)  { W = w2;  K = 128; local = g - GO_W2; }
    else if (g < GO_W4)  { W = w3;  K = 128; local = g - GO_W3; }
    else                 { W = w4;  K = 128; local = g - GO_W4; }
    const int lane = local & 63, fb = local >> 6;
    const int ksteps = K >> 5;
    const int ks = fb % ksteps, n0g = fb / ksteps;
    const int n  = n0g * 16 + (lane & 15);
    const int k0 = ks * 32 + (lane >> 4) * 8;
    ws[g] = cvt8(W + (size_t)n * K + k0);
  } else {                          // mw3: AdaIN-interleaved
    const int local = g - GO_MW3;
    const int lane = local & 63, fb = local >> 6;   // fb: l(2) ch(1) tt(2) sb(1) ks(2)
    const int ks = fb & 3, sb = (fb >> 2) & 1, tt = (fb >> 3) & 3;
    const int ch = (fb >> 5) & 1, l = fb >> 6;
    const int n  = l * 256 + 2 * (ch * 64 + tt * 16 + (lane & 15)) + sb;
    const int k0 = ks * 32 + (lane >> 4) * 8;
    ws[g] = cvt8(mw3 + (size_t)n * 128 + k0);
  }
}

template<bool WS>
__device__ __forceinline__ f16x8 ldB(const f16x8* __restrict__ wp,
                                     const float* __restrict__ wf,
                                     int K, int n0, int ks, int lane) {
  if constexpr (WS) {
    return wp[((n0 >> 4) * (K >> 5) + ks) * 64 + lane];
  } else {
    const int n  = n0 + (lane & 15);
    const int k0 = ks * 32 + (lane >> 4) * 8;
    return cvt8(wf + (size_t)n * K + k0);
  }
}

template<bool WS>
__device__ __forceinline__ f16x8 ldB3(const f16x8* __restrict__ wp,
                                      const float* __restrict__ wf,
                                      int l, int ch, int tt, int sb, int ks, int lane) {
  if constexpr (WS) {
    const int fb = (((l * 2 + ch) * 4 + tt) * 2 + sb) * 4 + ks;
    return wp[fb * 64 + lane];
  } else {
    const int n  = l * 256 + 2 * (ch * 64 + tt * 16 + (lane & 15)) + sb;
    const int k0 = ks * 32 + (lane >> 4) * 8;
    return cvt8(wf + (size_t)n * 128 + k0);
  }
}

template<bool WS>
__device__ __forceinline__ f16x4 ldB1(const f16x8* __restrict__ wsp,
                                      const float* __restrict__ mw1f,
                                      int jt, int lane) {
  if constexpr (WS) {
    return ((const f16x4*)(wsp + G_TOT))[jt * 64 + lane];
  } else {
    const int j = jt * 16 + (lane & 15);
    const int k0 = (lane >> 4) * 4;
    return cvt4v(*(const float4*)(mw1f + j * 16 + k0));
  }
}

#define MFMA(a, b, c)   __builtin_amdgcn_mfma_f32_16x16x32_f16((a), (b), (c), 0, 0, 0)
#define MFMA16(a, b, c) __builtin_amdgcn_mfma_f32_16x16x16f16((a), (b), (c), 0, 0, 0)

// ---- phase-B ks-pipeline macros (named buffers, literal indices) ----
#define LD_AY(BUF, KS) _Pragma("unroll") for (int p_ = 0; p_ < 4; ++p_)     \
  BUF[p_] = *(const f16x8*)&sY[p_ * 16 + ln][(KS) * 32 + acol];

#define LD_BM(BUF, KS) _Pragma("unroll") for (int tt_ = 0; tt_ < 4; ++tt_)  \
  BUF[tt_] = ldB<WS>(Wp_, Wf_, 128, ch * 64 + tt_ * 16, (KS), lane);

#define B_STEP(AYB, BMB) _Pragma("unroll") for (int tt_ = 0; tt_ < 4; ++tt_) \
  _Pragma("unroll") for (int p_ = 0; p_ < 4; ++p_)                          \
    accM[p_][tt_] = MFMA(BMB[tt_], AYB[p_], accM[p_][tt_]);

template<bool WS>
__global__ __launch_bounds__(NTHR, 2)   // 2 waves/EU band; arch-VGPR budget ~128
void adain_mfma(const float* __restrict__ x,   const float* __restrict__ meta,
                const float* __restrict__ mw1, const float* __restrict__ mb1,
                const float* __restrict__ mw2, const float* __restrict__ mb2,
                const float* __restrict__ mw3, const float* __restrict__ mb3,
                const float* __restrict__ w1,  const float* __restrict__ b1,
                const float* __restrict__ w2,  const float* __restrict__ b2,
                const float* __restrict__ w3,  const float* __restrict__ b3,
                const float* __restrict__ w4,  const float* __restrict__ b4,
                const float* __restrict__ w5,  const float* __restrict__ b5,
                const f16x8* __restrict__ wsp, float* __restrict__ out)
{
  __shared__ __align__(16) char smem[SMEM_SZ];
  f16    (*sH2)[136]   = (f16(*)[136])  (smem + OFF_H2);
  f16    (*sH1)[72]    = (f16(*)[72])   (smem + OFF_H1);
  f16    (*sY)[136]    = (f16(*)[136])  (smem + OFF_B);
  float2 (*sStats)[2]  = (float2(*)[2]) (smem + OFF_STATS);
  float  (*sOut)[2]    = (float(*)[2])  (smem + OFF_OUT);
  float  *sX           = (float*)       (smem + OFF_X);

  const int t    = threadIdx.x;
  const int lane = t & 63;
  const int ch   = t >> 6;            // wave id == column half
  const int r0   = blockIdx.x * RPB;
  const int ln   = lane & 15;         // row index within 16-row stripe (D^T layout)
  const int bg   = lane >> 4;         // k-subgroup / channel quad
  const int acol = bg * 8;
  const int g4   = bg * 4;            // channel base offset within 16-chan tile

  const f16x8* wsp3 = wsp + GO_MW3;

  // ---- stage x (consumed after h1 barrier) ----
  if (t < RPB) sX[t] = x[r0 + t];

  // ---- h1 = relu(meta @ mw1.T + mb1) via MFMA 16x16x16, meta from global ----
  {
    f16x4 am[4];
#pragma unroll
    for (int p = 0; p < 4; ++p)
      am[p] = cvt4v(*(const float4*)(meta + (size_t)(r0 + p * 16 + ln) * 16 + g4));
#pragma unroll
    for (int jj = 0; jj < 2; ++jj) {
      const int jt = ch * 2 + jj;
      const f16x4 wj = ldB1<WS>(wsp, mw1, jt, lane);
      const float4 bb = *(const float4*)(mb1 + jt * 16 + g4);
      const f32x4 cini = {bb.x, bb.y, bb.z, bb.w};
#pragma unroll
      for (int p = 0; p < 4; ++p) {
        f32x4 acc = MFMA16(wj, am[p], cini);
        f16x4 hv;
#pragma unroll
        for (int q = 0; q < 4; ++q) hv[q] = (f16)fmaxf(acc[q], 0.0f);
        *(f16x4*)&sH1[p * 16 + ln][jt * 16 + g4] = hv;
      }
    }
  }
  __syncthreads();

  // ---- h2 = relu(h1 @ mw2.T + mb2), transposed-D, bias in C ----
  {
    f16x8 a0[4], a1[4];
#pragma unroll
    for (int p = 0; p < 4; ++p) {
      const int ar = p * 16 + ln;
      a0[p] = *(const f16x8*)&sH1[ar][acol];
      a1[p] = *(const f16x8*)&sH1[ar][32 + acol];
    }
#pragma unroll
    for (int tt = 0; tt < 4; ++tt) {
      const int n0 = ch * 64 + tt * 16;
      f16x8 b0 = ldB<WS>(wsp + GO_MW2, mw2, 64, n0, 0, lane);
      f16x8 b1 = ldB<WS>(wsp + GO_MW2, mw2, 64, n0, 1, lane);
      const float4 bb = *(const float4*)(mb2 + n0 + g4);
      const f32x4 cini = {bb.x, bb.y, bb.z, bb.w};
#pragma unroll
      for (int p = 0; p < 4; ++p) {
        f32x4 acc = MFMA(b0, a0[p], cini);
        acc = MFMA(b1, a1[p], acc);
        f16x4 hv;
#pragma unroll
        for (int q = 0; q < 4; ++q) hv[q] = (f16)fmaxf(acc[q], 0.0f);
        *(f16x4*)&sH2[p * 16 + ln][n0 + g4] = hv;
      }
    }
  }
  __syncthreads();

  // ---- 4 AdaIN layers: main (f32) -> stats -> z into sY slots -> style+apply ----
#pragma unroll 1
  for (int l = 0; l < 4; ++l) {
    // ---- phase B: main pre-activation (transposed-D, bias in C, ks-pipelined) ----
    f32x4 accM[4][4];

    if (l == 0) {
#pragma unroll
      for (int tt = 0; tt < 4; ++tt) {
        const int c4 = ch * 64 + tt * 16 + g4;
        const float4 w1v = *(const float4*)(w1 + c4);
        const float4 b1v = *(const float4*)(b1 + c4);
#pragma unroll
        for (int p = 0; p < 4; ++p) {
          const float xv = sX[p * 16 + ln];
          accM[p][tt][0] = xv * w1v.x + b1v.x;
          accM[p][tt][1] = xv * w1v.y + b1v.y;
          accM[p][tt][2] = xv * w1v.z + b1v.z;
          accM[p][tt][3] = xv * w1v.w + b1v.w;
        }
      }
    } else {
      const f16x8* Wp_ = (l == 1) ? wsp + GO_W2 : (l == 2) ? wsp + GO_W3 : wsp + GO_W4;
      const float* Wf_ = (l == 1) ? w2 : (l == 2) ? w3 : w4;
      const float* Bv_ = (l == 1) ? b2 : (l == 2) ? b3 : b4;
#pragma unroll
      for (int tt = 0; tt < 4; ++tt) {
        const float4 bv = *(const float4*)(Bv_ + ch * 64 + tt * 16 + g4);
        const f32x4 cini = {bv.x, bv.y, bv.z, bv.w};
#pragma unroll
        for (int p = 0; p < 4; ++p)
          accM[p][tt] = cini;
      }
      // ks-pipelined, phase-local double buffers (arch-pressure-safe: accM in accregs)
      f16x8 aYA[4], aYB[4], bmA[4], bmB[4];
      LD_AY(aYA, 0); LD_BM(bmA, 0);
      LD_AY(aYB, 1); LD_BM(bmB, 1);
      B_STEP(aYA, bmA);
      LD_AY(aYA, 2); LD_BM(bmA, 2);
      B_STEP(aYB, bmB);
      LD_AY(aYB, 3); LD_BM(bmB, 3);
      B_STEP(aYA, bmA);
      B_STEP(aYB, bmB);
    }

    // ---- stats: scalar per stripe ----
    float s1[4] = {0,0,0,0}, s2[4] = {0,0,0,0};
#pragma unroll
    for (int p = 0; p < 4; ++p)
#pragma unroll
      for (int tt = 0; tt < 4; ++tt)
#pragma unroll
        for (int q = 0; q < 4; ++q) {
          const float v = accM[p][tt][q];
          s1[p] += v; s2[p] += v * v;
        }
#pragma unroll
    for (int p = 0; p < 4; ++p) {
      s1[p] += __shfl_xor(s1[p], 16, 64);
      s2[p] += __shfl_xor(s2[p], 16, 64);
      s1[p] += __shfl_xor(s1[p], 32, 64);
      s2[p] += __shfl_xor(s2[p], 32, 64);
    }
    if (lane < 16) {
#pragma unroll
      for (int p = 0; p < 4; ++p)
        sStats[p * 16 + ln][ch] = make_float2(s1[p], s2[p]);
    }
    __syncthreads();   // retires prev-y reads; sY slots reusable for z

    // ---- mu/rsg; z = (v-mu)*rsg f16 -> staged in sY slots ----
#pragma unroll
    for (int p = 0; p < 4; ++p) {
      const int r = p * 16 + ln;
      const float2 A = sStats[r][0], Bc = sStats[r][1];
      const float S1 = A.x + Bc.x, S2 = A.y + Bc.y;
      const float m = S1 * (1.0f / 128.0f);
      float var = (S2 - S1 * m) * (1.0f / 127.0f);
      var = fmaxf(var, 0.0f);
      const float rsg = 1.0f / (sqrtf(var) + 1e-6f);
#pragma unroll
      for (int tt = 0; tt < 4; ++tt) {
        f16x4 zv;
#pragma unroll
        for (int q = 0; q < 4; ++q)
          zv[q] = (f16)((accM[p][tt][q] - m) * rsg);
        *(f16x4*)&sY[r][ch * 64 + tt * 16 + g4] = zv;
      }
    }

    // ---- phase A: style MFMA (transposed, mb3 in C) + apply, per tt ----
    f16x8 aH[4][4];
#pragma unroll
    for (int p = 0; p < 4; ++p) {
      const int ar = p * 16 + ln;
#pragma unroll
      for (int ks = 0; ks < 4; ++ks)
        aH[p][ks] = *(const f16x8*)&sH2[ar][ks * 32 + acol];
    }

    if (l < 3) {
#pragma unroll
      for (int tt = 0; tt < 4; ++tt) {
        const int c4 = ch * 64 + tt * 16 + g4;
        const float4 mv0 = *(const float4*)(mb3 + l * 256 + 2 * c4);      // s0 b0 s1 b1
        const float4 mv1 = *(const float4*)(mb3 + l * 256 + 2 * c4 + 4);  // s2 b2 s3 b3
        const f32x4 scI = {mv0.x, mv0.z, mv1.x, mv1.z};
        const f32x4 biI = {mv0.y, mv0.w, mv1.y, mv1.w};
        f32x4 sc[4], bi[4];
#pragma unroll
        for (int p = 0; p < 4; ++p) { sc[p] = scI; bi[p] = biI; }
#pragma unroll
        for (int ks = 0; ks < 4; ++ks) {
          const f16x8 bs0 = ldB3<WS>(wsp3, mw3, l, ch, tt, 0, ks, lane);
          const f16x8 bs1 = ldB3<WS>(wsp3, mw3, l, ch, tt, 1, ks, lane);
#pragma unroll
          for (int p = 0; p < 4; ++p) {
            sc[p] = MFMA(bs0, aH[p][ks], sc[p]);
            bi[p] = MFMA(bs1, aH[p][ks], bi[p]);
          }
        }
#pragma unroll
        for (int p = 0; p < 4; ++p) {
          const int r = p * 16 + ln;
          const f16x4 zv = *(const f16x4*)&sY[r][c4];    // same-thread slot
          f16x4 yv;
#pragma unroll
          for (int q = 0; q < 4; ++q) {
            float v = sc[p][q] * (float)zv[q] + bi[p][q];
            v = fmaxf(v, 0.01f * v);
            yv[q] = (f16)v;
          }
          *(f16x4*)&sY[r][c4] = yv;                      // overwrite z with y
        }
      }
      __syncthreads();
    } else {
      float o[4] = {0, 0, 0, 0};
#pragma unroll
      for (int tt = 0; tt < 4; ++tt) {
        const int c4 = ch * 64 + tt * 16 + g4;
        const float4 mv0 = *(const float4*)(mb3 + l * 256 + 2 * c4);
        const float4 mv1 = *(const float4*)(mb3 + l * 256 + 2 * c4 + 4);
        const f32x4 scI = {mv0.x, mv0.z, mv1.x, mv1.z};
        const f32x4 biI = {mv0.y, mv0.w, mv1.y, mv1.w};
        const float4 w5v = *(const float4*)(w5 + c4);
        const float w5q[4] = {w5v.x, w5v.y, w5v.z, w5v.w};
        f32x4 sc[4], bi[4];
#pragma unroll
        for (int p = 0; p < 4; ++p) { sc[p] = scI; bi[p] = biI; }
#pragma unroll
        for (int ks = 0; ks < 4; ++ks) {
          const f16x8 bs0 = ldB3<WS>(wsp3, mw3, l, ch, tt, 0, ks, lane);
          const f16x8 bs1 = ldB3<WS>(wsp3, mw3, l, ch, tt, 1, ks, lane);
#pragma unroll
          for (int p = 0; p < 4; ++p) {
            sc[p] = MFMA(bs0, aH[p][ks], sc[p]);
            bi[p] = MFMA(bs1, aH[p][ks], bi[p]);
          }
        }
#pragma unroll
        for (int p = 0; p < 4; ++p) {
          const f16x4 zv = *(const f16x4*)&sY[p * 16 + ln][c4];
#pragma unroll
          for (int q = 0; q < 4; ++q) {
            float v = sc[p][q] * (float)zv[q] + bi[p][q];
            v = fmaxf(v, 0.01f * v);
            o[p] += v * w5q[q];
          }
        }
      }
#pragma unroll
      for (int p = 0; p < 4; ++p) {
        o[p] += __shfl_xor(o[p], 16, 64);
        o[p] += __shfl_xor(o[p], 32, 64);
      }
      if (lane < 16) {
#pragma unroll
        for (int p = 0; p < 4; ++p)
          sOut[p * 16 + ln][ch] = o[p];
      }
      __syncthreads();
      if (t < RPB) {
        float v = sOut[t][0] + sOut[t][1] + b5[0];
        v = fmaxf(v, 0.01f * v);
        out[r0 + t] = v;
      }
    }
  }
}

extern "C" void kernel_launch(void* const* d_in, const int* in_sizes, int n_in,
                              void* d_out, int out_size, void* d_ws, size_t ws_size,
                              hipStream_t stream) {
  const float* x    = (const float*)d_in[0];
  const float* meta = (const float*)d_in[1];
  const float* mw1  = (const float*)d_in[2];
  const float* mb1  = (const float*)d_in[3];
  const float* mw2  = (const float*)d_in[4];
  const float* mb2  = (const float*)d_in[5];
  const float* mw3  = (const float*)d_in[6];
  const float* mb3  = (const float*)d_in[7];
  const float* w1   = (const float*)d_in[8];
  const float* b1   = (const float*)d_in[9];
  const float* w2   = (const float*)d_in[10];
  const float* b2   = (const float*)d_in[11];
  const float* w3   = (const float*)d_in[12];
  const float* b3   = (const float*)d_in[13];
  const float* w4   = (const float*)d_in[14];
  const float* b4   = (const float*)d_in[15];
  const float* w5   = (const float*)d_in[16];
  const float* b5   = (const float*)d_in[17];
  float* out = (float*)d_out;

  const int nrows = in_sizes[0];        // 262144
  const int grid  = nrows / RPB;        // 4096

  const bool usews = (ws_size >= WS_BYTES) && (d_ws != nullptr);
  if (usews) {
    f16x8* wsp = (f16x8*)d_ws;
    hipLaunchKernelGGL(pack_weights, dim3((G_TOT + G_MW1Q + 255) / 256), dim3(256), 0, stream,
                       mw1, mw2, w2, w3, w4, mw3, wsp);
    hipLaunchKernelGGL(adain_mfma<true>, dim3(grid), dim3(NTHR), 0, stream,
                       x, meta, mw1, mb1, mw2, mb2, mw3, mb3,
                       w1, b1, w2, b2, w3, b3, w4, b4, w5, b5, wsp, out);
  } else {
    hipLaunchKernelGGL(adain_mfma<false>, dim3(grid), dim3(NTHR), 0, stream,
                       x, meta, mw1, mb1, mw2, mb2, mw3, mb3,
                       w1, b1, w2, b2, w3, b3, w4, b4, w5, b5, (const f16x8*)nullptr, out);
  }
}